// Round 2
// baseline (13045.288 us; speedup 1.0000x reference)
//
#include <hip/hip_runtime.h>

typedef unsigned short u16;
typedef __attribute__((ext_vector_type(8))) short short8;
typedef __attribute__((ext_vector_type(4))) float f32x4;

#define HH 1024
#define BB 64
#define TT 512
#define G3 3072
#define NBLK 192

__device__ __forceinline__ u16 f2b(float f) {
  unsigned u = __float_as_uint(f);
  unsigned r = (u + 0x7fffu + ((u >> 16) & 1u)) >> 16;
  return (u16)r;
}
__device__ __forceinline__ float b2f(u16 h) {
  return __uint_as_float(((unsigned)h) << 16);
}

// ---------------- elementwise converts / init / finalize ----------------

__global__ void f32_to_bf16_k(const float* __restrict__ s, u16* __restrict__ d, int n) {
  int stride = gridDim.x * blockDim.x * 4;
  for (int i = (blockIdx.x * blockDim.x + threadIdx.x) * 4; i < n; i += stride) {
    float4 v = *(const float4*)(s + i);
    uint2 p;
    p.x = (unsigned)f2b(v.x) | ((unsigned)f2b(v.y) << 16);
    p.y = (unsigned)f2b(v.z) | ((unsigned)f2b(v.w) << 16);
    *(uint2*)(d + i) = p;
  }
}

__global__ void init_h_k(const float* __restrict__ h0in, float* __restrict__ h0f,
                         float* __restrict__ h1f, u16* __restrict__ h0b,
                         u16* __restrict__ h1b) {
  int i = blockIdx.x * blockDim.x + threadIdx.x;
  if (i < BB * HH) {
    float a = h0in[i];
    h0f[i] = a; h0b[i] = f2b(a);
    float b = h0in[BB * HH + i];
    h1f[i] = b; h1b[i] = f2b(b);
  }
}

__global__ void finalize_k(const float* __restrict__ h0f, const float* __restrict__ h1f,
                           float* __restrict__ out) {
  int i = blockIdx.x * blockDim.x + threadIdx.x;
  if (i < BB * HH) {
    out[i] = h0f[i];
    out[BB * HH + i] = h1f[i];
  }
}

// ---------------- phase A: xg0 = bf16(x @ W_ih0^T + b_ih0) ----------------

__global__ __launch_bounds__(256) void gemm_xg_k(
    const u16* __restrict__ A, const u16* __restrict__ Wt,
    const float* __restrict__ bias, u16* __restrict__ C) {
  const int bm = blockIdx.x / 24;
  const int bn = blockIdx.x % 24;
  const int m0 = bm * 128, n0 = bn * 128;
  __shared__ __align__(16) u16 al[128 * 40];
  __shared__ __align__(16) u16 bl[128 * 40];
  const int tid = threadIdx.x;
  const int w = tid >> 6, l = tid & 63;
  const int wr = w >> 1, wc = w & 1;
  const int c0 = tid, c1 = tid + 256;
  const int r0 = c0 >> 2, s0 = c0 & 3, r1 = c1 >> 2, s1 = c1 & 3;

  const f32x4 fzero = {0.f, 0.f, 0.f, 0.f};
  f32x4 acc[4][4];
#pragma unroll
  for (int i = 0; i < 4; ++i)
#pragma unroll
    for (int j = 0; j < 4; ++j) acc[i][j] = fzero;

  const u16* a0p = A + (size_t)(m0 + r0) * 1024 + s0 * 8;
  const u16* a1p = A + (size_t)(m0 + r1) * 1024 + s1 * 8;
  const u16* b0p = Wt + (size_t)(n0 + r0) * 1024 + s0 * 8;
  const u16* b1p = Wt + (size_t)(n0 + r1) * 1024 + s1 * 8;

  int4 va0 = *(const int4*)(a0p);
  int4 va1 = *(const int4*)(a1p);
  int4 vb0 = *(const int4*)(b0p);
  int4 vb1 = *(const int4*)(b1p);

  for (int kt = 0; kt < 32; ++kt) {
    __syncthreads();
    *(int4*)&al[r0 * 40 + s0 * 8] = va0;
    *(int4*)&al[r1 * 40 + s1 * 8] = va1;
    *(int4*)&bl[r0 * 40 + s0 * 8] = vb0;
    *(int4*)&bl[r1 * 40 + s1 * 8] = vb1;
    __syncthreads();
    if (kt < 31) {
      va0 = *(const int4*)(a0p + (kt + 1) * 32);
      va1 = *(const int4*)(a1p + (kt + 1) * 32);
      vb0 = *(const int4*)(b0p + (kt + 1) * 32);
      vb1 = *(const int4*)(b1p + (kt + 1) * 32);
    }
    short8 af[4], bf[4];
#pragma unroll
    for (int i = 0; i < 4; ++i)
      af[i] = *(const short8*)&al[(wr * 64 + i * 16 + (l & 15)) * 40 + (l >> 4) * 8];
#pragma unroll
    for (int j = 0; j < 4; ++j)
      bf[j] = *(const short8*)&bl[(wc * 64 + j * 16 + (l & 15)) * 40 + (l >> 4) * 8];
#pragma unroll
    for (int i = 0; i < 4; ++i)
#pragma unroll
      for (int j = 0; j < 4; ++j)
        acc[i][j] = __builtin_amdgcn_mfma_f32_16x16x32_bf16(af[i], bf[j], acc[i][j], 0, 0, 0);
  }

#pragma unroll
  for (int i = 0; i < 4; ++i) {
#pragma unroll
    for (int j = 0; j < 4; ++j) {
      int col = n0 + wc * 64 + j * 16 + (l & 15);
      float bv = bias[col];
#pragma unroll
      for (int q = 0; q < 4; ++q) {
        int row = m0 + wr * 64 + i * 16 + (l >> 4) * 4 + q;
        C[(size_t)row * G3 + col] = f2b(acc[i][j][q] + bv);
      }
    }
  }
}

// ---------------- persistent fused scan ----------------
// One launch. 192 blocks x 256 threads, 96 KB LDS => exactly 1 block/CU on
// 256 CUs => all blocks co-resident => manual grid barrier is safe.
//  part0 (blk 0..63):    layer0 step t      (active t<=511)
//  part1 (blk 64..127):  xg1 for step t-1   (active 1<=t<=512)
//  part2 (blk 128..191): layer1 step t-2    (active 2<=t<=513)
// W slice (48x1024 bf16, XOR-swizzled) staged in LDS ONCE before the t-loop.
// Cross-step deps cross an agent-scope barrier (release-wbl2 / acquire-inv).

__global__ __launch_bounds__(256, 1) void gru_scan_k(
    const u16* __restrict__ xg0,
    const u16* __restrict__ whh0, const u16* __restrict__ wih1,
    const u16* __restrict__ whh1,
    const float* __restrict__ bhh0, const float* __restrict__ bih1,
    const float* __restrict__ bhh1,
    float* __restrict__ h0f, float* __restrict__ h1f,
    u16* __restrict__ h0b, u16* __restrict__ h1b,
    float* __restrict__ xg1, unsigned* __restrict__ bar) {
  const int blk = blockIdx.x;
  const int part = blk >> 6;
  const int sub = blk & 63;
  const int tid = threadIdx.x;
  const int w = tid >> 6, l = tid & 63;

  const u16* Wsrc;
  int off0, off1, off2;
  if (part == 0) {
    Wsrc = whh0; off0 = sub * 16; off1 = HH + sub * 16; off2 = 2 * HH + sub * 16;
  } else if (part == 1) {
    Wsrc = wih1; off0 = sub * 48; off1 = sub * 48 + 16; off2 = sub * 48 + 32;
  } else {
    Wsrc = whh1; off0 = sub * 16; off1 = HH + sub * 16; off2 = 2 * HH + sub * 16;
  }

  __shared__ __align__(16) u16 wlds[48 * 1024];
  for (int i = tid; i < 6144; i += 256) {
    int r = i >> 7;
    int c = i & 127;
    int g = r >> 4;
    int wrow = (g == 0 ? off0 : (g == 1 ? off1 : off2)) + (r & 15);
    int4 v = *(const int4*)(Wsrc + (size_t)wrow * 1024 + c * 8);
    int idx = r * 1024 + ((c * 8) ^ ((r & 7) << 3));
    *(int4*)&wlds[idx] = v;
  }
  __syncthreads();

  const int lrow = l & 15;
  const int kb = (l >> 4) * 8;
  const int rr0 = lrow, rr1 = 16 + lrow, rr2 = 32 + lrow;
  const int sx0 = (rr0 & 7) << 3, sx1 = (rr1 & 7) << 3, sx2 = (rr2 & 7) << 3;
  const u16* Abase = (part == 2) ? h1b : h0b;
  const size_t arow = (size_t)(w * 16 + lrow) * HH + kb;
  const int j = sub * 16 + lrow;

  for (int t = 0; t <= 513; ++t) {
    const int p0 = t & 1;
    const bool active = (part == 0) ? (t <= 511)
                      : (part == 1) ? (t >= 1 && t <= 512)
                                    : (t >= 2);
    if (active) {
      const u16* Ap = Abase + (size_t)p0 * (BB * HH) + arow;
      const f32x4 fzero = {0.f, 0.f, 0.f, 0.f};
      f32x4 acc0 = fzero, acc1 = fzero, acc2 = fzero;

      short8 abuf[16];
#pragma unroll
      for (int i = 0; i < 16; ++i) abuf[i] = *(const short8*)(Ap + i * 32);
#pragma unroll
      for (int ks = 0; ks < 32; ++ks) {
        short8 a = abuf[ks & 15];
        if (ks < 16) abuf[ks] = *(const short8*)(Ap + (ks + 16) * 32);
        int ke = kb + ks * 32;
        short8 b0 = *(const short8*)&wlds[rr0 * 1024 + (ke ^ sx0)];
        short8 b1 = *(const short8*)&wlds[rr1 * 1024 + (ke ^ sx1)];
        short8 b2 = *(const short8*)&wlds[rr2 * 1024 + (ke ^ sx2)];
        acc0 = __builtin_amdgcn_mfma_f32_16x16x32_bf16(a, b0, acc0, 0, 0, 0);
        acc1 = __builtin_amdgcn_mfma_f32_16x16x32_bf16(a, b1, acc1, 0, 0, 0);
        acc2 = __builtin_amdgcn_mfma_f32_16x16x32_bf16(a, b2, acc2, 0, 0, 0);
      }

      if (part == 1) {
        float* ox = xg1 + (size_t)(1 - p0) * (BB * G3);
        const int cc0 = off0 + lrow, cc1 = off1 + lrow, cc2 = off2 + lrow;
        const float bv0 = bih1[cc0], bv1 = bih1[cc1], bv2 = bih1[cc2];
#pragma unroll
        for (int q = 0; q < 4; ++q) {
          int row = w * 16 + (l >> 4) * 4 + q;
          ox[row * G3 + cc0] = acc0[q] + bv0;
          ox[row * G3 + cc1] = acc1[q] + bv1;
          ox[row * G3 + cc2] = acc2[q] + bv2;
        }
      } else {
        const float* hfo; float* hfn; u16* hbn; const float* bias;
        if (part == 0) {
          hfo = h0f + (size_t)p0 * (BB * HH); hfn = h0f + (size_t)(1 - p0) * (BB * HH);
          hbn = h0b + (size_t)(1 - p0) * (BB * HH); bias = bhh0;
        } else {
          hfo = h1f + (size_t)p0 * (BB * HH); hfn = h1f + (size_t)(1 - p0) * (BB * HH);
          hbn = h1b + (size_t)(1 - p0) * (BB * HH); bias = bhh1;
        }
        const float br = bias[j], bz = bias[HH + j], bn_ = bias[2 * HH + j];
#pragma unroll
        for (int q = 0; q < 4; ++q) {
          int row = w * 16 + (l >> 4) * 4 + q;
          float xr, xz, xn;
          if (part == 0) {
            const u16* xp = xg0 + (size_t)(t * BB + row) * G3;
            xr = b2f(xp[j]); xz = b2f(xp[HH + j]); xn = b2f(xp[2 * HH + j]);
          } else {
            const float* xp = xg1 + (size_t)p0 * (BB * G3) + row * G3;
            xr = xp[j]; xz = xp[HH + j]; xn = xp[2 * HH + j];
          }
          float rr = acc0[q] + br + xr;
          float zz = acc1[q] + bz + xz;
          float nn = acc2[q] + bn_;
          float r = 1.f / (1.f + __expf(-rr));
          float z = 1.f / (1.f + __expf(-zz));
          float n = tanhf(xn + r * nn);
          float ho = hfo[row * HH + j];
          float hv = (1.f - z) * n + z * ho;
          hfn[row * HH + j] = hv;
          hbn[row * HH + j] = f2b(hv);
        }
      }
    }

    // ---- grid barrier (agent scope, monotonic counter) ----
    __syncthreads();
    if (tid == 0) {
      __builtin_amdgcn_fence(__ATOMIC_RELEASE, "agent");
      __hip_atomic_fetch_add(bar, 1u, __ATOMIC_RELAXED, __HIP_MEMORY_SCOPE_AGENT);
      const unsigned target = (unsigned)(t + 1) * NBLK;
      while (__hip_atomic_load(bar, __ATOMIC_RELAXED, __HIP_MEMORY_SCOPE_AGENT) < target)
        __builtin_amdgcn_s_sleep(2);
      __builtin_amdgcn_fence(__ATOMIC_ACQUIRE, "agent");
    }
    __syncthreads();
  }
}

// ---------------- host ----------------

extern "C" void kernel_launch(void* const* d_in, const int* in_sizes, int n_in,
                              void* d_out, int out_size, void* d_ws, size_t ws_size,
                              hipStream_t stream) {
  const float* x   = (const float*)d_in[0];
  const float* h0  = (const float*)d_in[1];
  const float* wih = (const float*)d_in[2];
  const float* whh = (const float*)d_in[3];
  const float* bih = (const float*)d_in[4];
  const float* bhh = (const float*)d_in[5];
  float* out = (float*)d_out;

  char* ws = (char*)d_ws;
  size_t off = 0;
  auto alloc = [&](size_t bytes) -> void* {
    void* p = ws + off;
    off += (bytes + 255) & ~(size_t)255;
    return p;
  };
  u16* xbf   = (u16*)alloc((size_t)TT * BB * HH * 2);        // 64 MB
  u16* wihb  = (u16*)alloc((size_t)2 * G3 * HH * 2);         // 12.6 MB
  u16* whhb  = (u16*)alloc((size_t)2 * G3 * HH * 2);         // 12.6 MB
  u16* xg0   = (u16*)alloc((size_t)TT * BB * G3 * 2);        // 201 MB
  float* h0f = (float*)alloc((size_t)2 * BB * HH * 4);
  float* h1f = (float*)alloc((size_t)2 * BB * HH * 4);
  u16* h0b   = (u16*)alloc((size_t)2 * BB * HH * 2);
  u16* h1b   = (u16*)alloc((size_t)2 * BB * HH * 2);
  float* xg1 = (float*)alloc((size_t)2 * BB * G3 * 4);
  unsigned* bar = (unsigned*)alloc(256);

  hipMemsetAsync(bar, 0, 256, stream);
  f32_to_bf16_k<<<2048, 256, 0, stream>>>(x, xbf, TT * BB * HH);
  f32_to_bf16_k<<<512, 256, 0, stream>>>(wih, wihb, 2 * G3 * HH);
  f32_to_bf16_k<<<512, 256, 0, stream>>>(whh, whhb, 2 * G3 * HH);
  init_h_k<<<256, 256, 0, stream>>>(h0, h0f, h1f, h0b, h1b);

  gemm_xg_k<<<6144, 256, 0, stream>>>(xbf, wihb, bih, xg0);

  gru_scan_k<<<NBLK, 256, 0, stream>>>(xg0,
                                       whhb, wihb + (size_t)G3 * HH, whhb + (size_t)G3 * HH,
                                       bhh, bih + G3, bhh + G3,
                                       h0f, h1f, h0b, h1b, xg1, bar);

  finalize_k<<<256, 256, 0, stream>>>(h0f, h1f, out);
}

// Round 3
// 11815.760 us; speedup vs baseline: 1.1041x; 1.1041x over previous
//
#include <hip/hip_runtime.h>

typedef unsigned short u16;
typedef __attribute__((ext_vector_type(8))) short short8;
typedef __attribute__((ext_vector_type(4))) float f32x4;

#define HH 1024
#define BB 64
#define TT 512
#define G3 3072
#define NBLK 192

__device__ __forceinline__ u16 f2b(float f) {
  unsigned u = __float_as_uint(f);
  unsigned r = (u + 0x7fffu + ((u >> 16) & 1u)) >> 16;
  return (u16)r;
}
__device__ __forceinline__ float b2f(u16 h) {
  return __uint_as_float(((unsigned)h) << 16);
}

// ---------------- elementwise converts / init ----------------

__global__ void f32_to_bf16_k(const float* __restrict__ s, u16* __restrict__ d, int n) {
  int stride = gridDim.x * blockDim.x * 4;
  for (int i = (blockIdx.x * blockDim.x + threadIdx.x) * 4; i < n; i += stride) {
    float4 v = *(const float4*)(s + i);
    uint2 p;
    p.x = (unsigned)f2b(v.x) | ((unsigned)f2b(v.y) << 16);
    p.y = (unsigned)f2b(v.z) | ((unsigned)f2b(v.w) << 16);
    *(uint2*)(d + i) = p;
  }
}

__global__ void init_h_k(const float* __restrict__ h0in, u16* __restrict__ h0b,
                         u16* __restrict__ h1b) {
  int i = blockIdx.x * blockDim.x + threadIdx.x;
  if (i < BB * HH) {
    h0b[i] = f2b(h0in[i]);
    h1b[i] = f2b(h0in[BB * HH + i]);
  }
}

// ---------------- phase A: xg0 = bf16(x @ W_ih0^T + b_ih0) ----------------

__global__ __launch_bounds__(256) void gemm_xg_k(
    const u16* __restrict__ A, const u16* __restrict__ Wt,
    const float* __restrict__ bias, u16* __restrict__ C) {
  const int bm = blockIdx.x / 24;
  const int bn = blockIdx.x % 24;
  const int m0 = bm * 128, n0 = bn * 128;
  __shared__ __align__(16) u16 al[128 * 40];
  __shared__ __align__(16) u16 bl[128 * 40];
  const int tid = threadIdx.x;
  const int w = tid >> 6, l = tid & 63;
  const int wr = w >> 1, wc = w & 1;
  const int c0 = tid, c1 = tid + 256;
  const int r0 = c0 >> 2, s0 = c0 & 3, r1 = c1 >> 2, s1 = c1 & 3;

  const f32x4 fzero = {0.f, 0.f, 0.f, 0.f};
  f32x4 acc[4][4];
#pragma unroll
  for (int i = 0; i < 4; ++i)
#pragma unroll
    for (int j = 0; j < 4; ++j) acc[i][j] = fzero;

  const u16* a0p = A + (size_t)(m0 + r0) * 1024 + s0 * 8;
  const u16* a1p = A + (size_t)(m0 + r1) * 1024 + s1 * 8;
  const u16* b0p = Wt + (size_t)(n0 + r0) * 1024 + s0 * 8;
  const u16* b1p = Wt + (size_t)(n0 + r1) * 1024 + s1 * 8;

  int4 va0 = *(const int4*)(a0p);
  int4 va1 = *(const int4*)(a1p);
  int4 vb0 = *(const int4*)(b0p);
  int4 vb1 = *(const int4*)(b1p);

  for (int kt = 0; kt < 32; ++kt) {
    __syncthreads();
    *(int4*)&al[r0 * 40 + s0 * 8] = va0;
    *(int4*)&al[r1 * 40 + s1 * 8] = va1;
    *(int4*)&bl[r0 * 40 + s0 * 8] = vb0;
    *(int4*)&bl[r1 * 40 + s1 * 8] = vb1;
    __syncthreads();
    if (kt < 31) {
      va0 = *(const int4*)(a0p + (kt + 1) * 32);
      va1 = *(const int4*)(a1p + (kt + 1) * 32);
      vb0 = *(const int4*)(b0p + (kt + 1) * 32);
      vb1 = *(const int4*)(b1p + (kt + 1) * 32);
    }
    short8 af[4], bf[4];
#pragma unroll
    for (int i = 0; i < 4; ++i)
      af[i] = *(const short8*)&al[(wr * 64 + i * 16 + (l & 15)) * 40 + (l >> 4) * 8];
#pragma unroll
    for (int j = 0; j < 4; ++j)
      bf[j] = *(const short8*)&bl[(wc * 64 + j * 16 + (l & 15)) * 40 + (l >> 4) * 8];
#pragma unroll
    for (int i = 0; i < 4; ++i)
#pragma unroll
      for (int j = 0; j < 4; ++j)
        acc[i][j] = __builtin_amdgcn_mfma_f32_16x16x32_bf16(af[i], bf[j], acc[i][j], 0, 0, 0);
  }

#pragma unroll
  for (int i = 0; i < 4; ++i) {
#pragma unroll
    for (int j = 0; j < 4; ++j) {
      int col = n0 + wc * 64 + j * 16 + (l & 15);
      float bv = bias[col];
#pragma unroll
      for (int q = 0; q < 4; ++q) {
        int row = m0 + wr * 64 + i * 16 + (l >> 4) * 4 + q;
        C[(size_t)row * G3 + col] = f2b(acc[i][j][q] + bv);
      }
    }
  }
}

// ---------------- persistent fused scan, W-in-registers ----------------
// 192 blocks x 256 thr, NO LDS, ~460 VGPR (1 wave/SIMD) => 1 block/CU,
// 192 <= 256 CUs => co-resident. Each wave holds its whole W slice (96
// short8 = 384 VGPR) for all 514 steps. f32 h state is block-private =>
// lives in 4 regs/lane. Grid barrier: per-block flag slot (plain atomic
// store, NO RMW) + all-blocks poll; release/acquire agent fences for
// h0b/h1b/xg1 coherence.
//  part0 (blk 0..63):    layer0 step t      (t<=511)
//  part1 (blk 64..127):  xg1 for step t-1   (1<=t<=512)
//  part2 (blk 128..191): layer1 step t-2    (t>=2)

__global__ __launch_bounds__(256, 1) void gru_scan2_k(
    const u16* __restrict__ xg0,
    const u16* __restrict__ whh0, const u16* __restrict__ wih1,
    const u16* __restrict__ whh1,
    const float* __restrict__ bhh0, const float* __restrict__ bih1,
    const float* __restrict__ bhh1,
    const float* __restrict__ h0in,
    u16* __restrict__ h0b, u16* __restrict__ h1b,
    float* __restrict__ xg1, float* __restrict__ out,
    unsigned* __restrict__ flags) {
  const int blk = blockIdx.x;
  const int part = blk >> 6;
  const int sub = blk & 63;
  const int tid = threadIdx.x;
  const int w = tid >> 6, l = tid & 63;
  const int lrow = l & 15;
  const int kb = (l >> 4) * 8;

  const u16* Wsrc;
  int off0, off1, off2;
  if (part == 0) {
    Wsrc = whh0; off0 = sub * 16; off1 = HH + sub * 16; off2 = 2 * HH + sub * 16;
  } else if (part == 1) {
    Wsrc = wih1; off0 = sub * 48; off1 = sub * 48 + 16; off2 = sub * 48 + 32;
  } else {
    Wsrc = whh1; off0 = sub * 16; off1 = HH + sub * 16; off2 = 2 * HH + sub * 16;
  }

  // ---- W slice into registers (static indexing only) ----
  short8 bw[3][32];
  {
    const u16* wp0 = Wsrc + (size_t)(off0 + lrow) * HH + kb;
    const u16* wp1 = Wsrc + (size_t)(off1 + lrow) * HH + kb;
    const u16* wp2 = Wsrc + (size_t)(off2 + lrow) * HH + kb;
#pragma unroll
    for (int ks = 0; ks < 32; ++ks) {
      bw[0][ks] = *(const short8*)(wp0 + ks * 32);
      bw[1][ks] = *(const short8*)(wp1 + ks * 32);
      bw[2][ks] = *(const short8*)(wp2 + ks * 32);
    }
  }

  const int j = sub * 16 + lrow;
  const int myrow0 = w * 16 + (l >> 4) * 4;  // rows myrow0..+3 for q=0..3

  float hreg[4] = {0.f, 0.f, 0.f, 0.f};
  float br = 0.f, bz = 0.f, bn_ = 0.f;
  float bv0 = 0.f, bv1 = 0.f, bv2 = 0.f;
  if (part == 0) {
    br = bhh0[j]; bz = bhh0[HH + j]; bn_ = bhh0[2 * HH + j];
#pragma unroll
    for (int q = 0; q < 4; ++q) hreg[q] = h0in[(myrow0 + q) * HH + j];
  } else if (part == 2) {
    br = bhh1[j]; bz = bhh1[HH + j]; bn_ = bhh1[2 * HH + j];
#pragma unroll
    for (int q = 0; q < 4; ++q) hreg[q] = h0in[BB * HH + (myrow0 + q) * HH + j];
  } else {
    bv0 = bih1[off0 + lrow]; bv1 = bih1[off1 + lrow]; bv2 = bih1[off2 + lrow];
  }

  const u16* Abase = (part == 2) ? h1b : h0b;
  const size_t arow = (size_t)(w * 16 + lrow) * HH + kb;

  for (int t = 0; t <= 513; ++t) {
    const int p0 = t & 1;
    const bool active = (part == 0) ? (t <= 511)
                      : (part == 1) ? (t >= 1 && t <= 512)
                                    : (t >= 2);
    if (active) {
      const u16* Ap = Abase + (size_t)p0 * (BB * HH) + arow;
      // prime 8-deep A ring
      short8 ar[8];
#pragma unroll
      for (int i = 0; i < 8; ++i) ar[i] = *(const short8*)(Ap + i * 32);

      // prefetch xg0 slice (part0 only) early so tail doesn't stall
      u16 xrv[4], xzv[4], xnv[4];
      if (part == 0) {
        const u16* xp = xg0 + (size_t)t * BB * G3;
#pragma unroll
        for (int q = 0; q < 4; ++q) {
          const u16* rp = xp + (size_t)(myrow0 + q) * G3;
          xrv[q] = rp[j]; xzv[q] = rp[HH + j]; xnv[q] = rp[2 * HH + j];
        }
      }
      float xg1v[3][4];
      if (part == 2) {
        const float* xp = xg1 + (size_t)p0 * (BB * G3);
#pragma unroll
        for (int q = 0; q < 4; ++q) {
          const float* rp = xp + (size_t)(myrow0 + q) * G3;
          xg1v[0][q] = rp[j]; xg1v[1][q] = rp[HH + j]; xg1v[2][q] = rp[2 * HH + j];
        }
      }

      const f32x4 fzero = {0.f, 0.f, 0.f, 0.f};
      f32x4 acc0 = fzero, acc1 = fzero, acc2 = fzero;
#pragma unroll
      for (int ks = 0; ks < 32; ++ks) {
        short8 a = ar[ks & 7];
        if (ks < 24) ar[ks & 7] = *(const short8*)(Ap + (ks + 8) * 32);
        acc0 = __builtin_amdgcn_mfma_f32_16x16x32_bf16(a, bw[0][ks], acc0, 0, 0, 0);
        acc1 = __builtin_amdgcn_mfma_f32_16x16x32_bf16(a, bw[1][ks], acc1, 0, 0, 0);
        acc2 = __builtin_amdgcn_mfma_f32_16x16x32_bf16(a, bw[2][ks], acc2, 0, 0, 0);
      }

      if (part == 1) {
        float* ox = xg1 + (size_t)(1 - p0) * (BB * G3);
        const int cc0 = off0 + lrow, cc1 = off1 + lrow, cc2 = off2 + lrow;
#pragma unroll
        for (int q = 0; q < 4; ++q) {
          int row = myrow0 + q;
          ox[(size_t)row * G3 + cc0] = acc0[q] + bv0;
          ox[(size_t)row * G3 + cc1] = acc1[q] + bv1;
          ox[(size_t)row * G3 + cc2] = acc2[q] + bv2;
        }
      } else {
        u16* hbn = ((part == 0) ? h0b : h1b) + (size_t)(1 - p0) * (BB * HH);
#pragma unroll
        for (int q = 0; q < 4; ++q) {
          float xr, xz, xn;
          if (part == 0) {
            xr = b2f(xrv[q]); xz = b2f(xzv[q]); xn = b2f(xnv[q]);
          } else {
            xr = xg1v[0][q]; xz = xg1v[1][q]; xn = xg1v[2][q];
          }
          float rr = acc0[q] + br + xr;
          float zz = acc1[q] + bz + xz;
          float nn = acc2[q] + bn_;
          float r = 1.f / (1.f + __expf(-rr));
          float z = 1.f / (1.f + __expf(-zz));
          float n = tanhf(xn + r * nn);
          float hv = (1.f - z) * n + z * hreg[q];
          hreg[q] = hv;
          hbn[(size_t)(myrow0 + q) * HH + j] = f2b(hv);
        }
      }
    }

    // ---- grid barrier: per-block flag store + all-poll (no RMW) ----
    __syncthreads();  // drains each wave's vmcnt, aligns block
    if (tid == 0) {
      __builtin_amdgcn_fence(__ATOMIC_RELEASE, "agent");  // wbl2: L2 -> LLC
      __hip_atomic_store(&flags[blk], (unsigned)(t + 1),
                         __ATOMIC_RELAXED, __HIP_MEMORY_SCOPE_AGENT);
    }
    const unsigned tgt = (unsigned)(t + 1);
    for (;;) {
      unsigned a0 = __hip_atomic_load(&flags[l], __ATOMIC_RELAXED, __HIP_MEMORY_SCOPE_AGENT);
      unsigned a1 = __hip_atomic_load(&flags[l + 64], __ATOMIC_RELAXED, __HIP_MEMORY_SCOPE_AGENT);
      unsigned a2 = __hip_atomic_load(&flags[l + 128], __ATOMIC_RELAXED, __HIP_MEMORY_SCOPE_AGENT);
      unsigned mn = a0 < a1 ? a0 : a1;
      mn = mn < a2 ? mn : a2;
      if (__all(mn >= tgt)) break;
      __builtin_amdgcn_s_sleep(1);
    }
    __builtin_amdgcn_fence(__ATOMIC_ACQUIRE, "agent");  // inv L1/L2
  }

  // ---- write h_n ----
  if (part == 0) {
#pragma unroll
    for (int q = 0; q < 4; ++q) out[(size_t)(myrow0 + q) * HH + j] = hreg[q];
  } else if (part == 2) {
#pragma unroll
    for (int q = 0; q < 4; ++q) out[BB * HH + (size_t)(myrow0 + q) * HH + j] = hreg[q];
  }
}

// ---------------- host ----------------

extern "C" void kernel_launch(void* const* d_in, const int* in_sizes, int n_in,
                              void* d_out, int out_size, void* d_ws, size_t ws_size,
                              hipStream_t stream) {
  const float* x   = (const float*)d_in[0];
  const float* h0  = (const float*)d_in[1];
  const float* wih = (const float*)d_in[2];
  const float* whh = (const float*)d_in[3];
  const float* bih = (const float*)d_in[4];
  const float* bhh = (const float*)d_in[5];
  float* out = (float*)d_out;

  char* ws = (char*)d_ws;
  size_t off = 0;
  auto alloc = [&](size_t bytes) -> void* {
    void* p = ws + off;
    off += (bytes + 255) & ~(size_t)255;
    return p;
  };
  u16* xbf   = (u16*)alloc((size_t)TT * BB * HH * 2);        // 64 MB
  u16* wihb  = (u16*)alloc((size_t)2 * G3 * HH * 2);         // 12.6 MB
  u16* whhb  = (u16*)alloc((size_t)2 * G3 * HH * 2);         // 12.6 MB
  u16* xg0   = (u16*)alloc((size_t)TT * BB * G3 * 2);        // 201 MB
  u16* h0b   = (u16*)alloc((size_t)2 * BB * HH * 2);
  u16* h1b   = (u16*)alloc((size_t)2 * BB * HH * 2);
  float* xg1 = (float*)alloc((size_t)2 * BB * G3 * 4);
  unsigned* flags = (unsigned*)alloc(NBLK * 4);

  hipMemsetAsync(flags, 0, NBLK * 4, stream);
  f32_to_bf16_k<<<2048, 256, 0, stream>>>(x, xbf, TT * BB * HH);
  f32_to_bf16_k<<<512, 256, 0, stream>>>(wih, wihb, 2 * G3 * HH);
  f32_to_bf16_k<<<512, 256, 0, stream>>>(whh, whhb, 2 * G3 * HH);
  init_h_k<<<256, 256, 0, stream>>>(h0, h0b, h1b);

  gemm_xg_k<<<6144, 256, 0, stream>>>(xbf, wihb, bih, xg0);

  gru_scan2_k<<<NBLK, 256, 0, stream>>>(xg0,
                                        whhb, wihb + (size_t)G3 * HH, whhb + (size_t)G3 * HH,
                                        bhh, bih + G3, bhh + G3, h0,
                                        h0b, h1b, xg1, out, flags);
}

// Round 4
// 7709.735 us; speedup vs baseline: 1.6921x; 1.5326x over previous
//
#include <hip/hip_runtime.h>

typedef unsigned short u16;
typedef unsigned long long u64;
typedef __attribute__((ext_vector_type(8))) short short8;
typedef __attribute__((ext_vector_type(4))) float f32x4;

#define HH 1024
#define BB 64
#define TT 512
#define G3 3072
#define NBLK 192

__device__ __forceinline__ u16 f2b(float f) {
  unsigned u = __float_as_uint(f);
  unsigned r = (u + 0x7fffu + ((u >> 16) & 1u)) >> 16;
  return (u16)r;
}
__device__ __forceinline__ float b2f(u16 h) {
  return __uint_as_float(((unsigned)h) << 16);
}

// agent-scope (LLC-coherent) accessors — per-access sc1, NO fences/wbl2/inv
__device__ __forceinline__ short8 ld_s8_agent(const u16* p) {
  union { short8 v; u64 d[2]; } s;
  s.d[0] = __hip_atomic_load((const u64*)p, __ATOMIC_RELAXED, __HIP_MEMORY_SCOPE_AGENT);
  s.d[1] = __hip_atomic_load((const u64*)(p + 4), __ATOMIC_RELAXED, __HIP_MEMORY_SCOPE_AGENT);
  return s.v;
}
__device__ __forceinline__ void st_u32_agent(unsigned* p, unsigned v) {
  __hip_atomic_store(p, v, __ATOMIC_RELAXED, __HIP_MEMORY_SCOPE_AGENT);
}
__device__ __forceinline__ unsigned ld_u32_agent(const unsigned* p) {
  return __hip_atomic_load(p, __ATOMIC_RELAXED, __HIP_MEMORY_SCOPE_AGENT);
}

// ---------------- elementwise converts / init ----------------

__global__ void f32_to_bf16_k(const float* __restrict__ s, u16* __restrict__ d, int n) {
  int stride = gridDim.x * blockDim.x * 4;
  for (int i = (blockIdx.x * blockDim.x + threadIdx.x) * 4; i < n; i += stride) {
    float4 v = *(const float4*)(s + i);
    uint2 p;
    p.x = (unsigned)f2b(v.x) | ((unsigned)f2b(v.y) << 16);
    p.y = (unsigned)f2b(v.z) | ((unsigned)f2b(v.w) << 16);
    *(uint2*)(d + i) = p;
  }
}

__global__ void init_h_k(const float* __restrict__ h0in, u16* __restrict__ h0b,
                         u16* __restrict__ h1b) {
  int i = blockIdx.x * blockDim.x + threadIdx.x;
  if (i < BB * HH) {
    h0b[i] = f2b(h0in[i]);
    h1b[i] = f2b(h0in[BB * HH + i]);
  }
}

// ---------------- phase A: xg0 = bf16(x @ W_ih0^T + b_ih0) ----------------

__global__ __launch_bounds__(256) void gemm_xg_k(
    const u16* __restrict__ A, const u16* __restrict__ Wt,
    const float* __restrict__ bias, u16* __restrict__ C) {
  const int bm = blockIdx.x / 24;
  const int bn = blockIdx.x % 24;
  const int m0 = bm * 128, n0 = bn * 128;
  __shared__ __align__(16) u16 al[128 * 40];
  __shared__ __align__(16) u16 bl[128 * 40];
  const int tid = threadIdx.x;
  const int w = tid >> 6, l = tid & 63;
  const int wr = w >> 1, wc = w & 1;
  const int c0 = tid, c1 = tid + 256;
  const int r0 = c0 >> 2, s0 = c0 & 3, r1 = c1 >> 2, s1 = c1 & 3;

  const f32x4 fzero = {0.f, 0.f, 0.f, 0.f};
  f32x4 acc[4][4];
#pragma unroll
  for (int i = 0; i < 4; ++i)
#pragma unroll
    for (int j = 0; j < 4; ++j) acc[i][j] = fzero;

  const u16* a0p = A + (size_t)(m0 + r0) * 1024 + s0 * 8;
  const u16* a1p = A + (size_t)(m0 + r1) * 1024 + s1 * 8;
  const u16* b0p = Wt + (size_t)(n0 + r0) * 1024 + s0 * 8;
  const u16* b1p = Wt + (size_t)(n0 + r1) * 1024 + s1 * 8;

  int4 va0 = *(const int4*)(a0p);
  int4 va1 = *(const int4*)(a1p);
  int4 vb0 = *(const int4*)(b0p);
  int4 vb1 = *(const int4*)(b1p);

  for (int kt = 0; kt < 32; ++kt) {
    __syncthreads();
    *(int4*)&al[r0 * 40 + s0 * 8] = va0;
    *(int4*)&al[r1 * 40 + s1 * 8] = va1;
    *(int4*)&bl[r0 * 40 + s0 * 8] = vb0;
    *(int4*)&bl[r1 * 40 + s1 * 8] = vb1;
    __syncthreads();
    if (kt < 31) {
      va0 = *(const int4*)(a0p + (kt + 1) * 32);
      va1 = *(const int4*)(a1p + (kt + 1) * 32);
      vb0 = *(const int4*)(b0p + (kt + 1) * 32);
      vb1 = *(const int4*)(b1p + (kt + 1) * 32);
    }
    short8 af[4], bf[4];
#pragma unroll
    for (int i = 0; i < 4; ++i)
      af[i] = *(const short8*)&al[(wr * 64 + i * 16 + (l & 15)) * 40 + (l >> 4) * 8];
#pragma unroll
    for (int j = 0; j < 4; ++j)
      bf[j] = *(const short8*)&bl[(wc * 64 + j * 16 + (l & 15)) * 40 + (l >> 4) * 8];
#pragma unroll
    for (int i = 0; i < 4; ++i)
#pragma unroll
      for (int j = 0; j < 4; ++j)
        acc[i][j] = __builtin_amdgcn_mfma_f32_16x16x32_bf16(af[i], bf[j], acc[i][j], 0, 0, 0);
  }

#pragma unroll
  for (int i = 0; i < 4; ++i) {
#pragma unroll
    for (int j = 0; j < 4; ++j) {
      int col = n0 + wc * 64 + j * 16 + (l & 15);
      float bv = bias[col];
#pragma unroll
      for (int q = 0; q < 4; ++q) {
        int row = m0 + wr * 64 + i * 16 + (l >> 4) * 4 + q;
        C[(size_t)row * G3 + col] = f2b(acc[i][j][q] + bv);
      }
    }
  }
}

// ---------------- persistent fused scan, fence-free coherence ----------------
// 192 blocks x 256 thr. Cross-block data (h0b/h1b, xg1, flags) uses per-access
// agent-scope atomics (sc1 -> LLC coherence point). Read-only data (W, xg0,
// biases) keeps normal cached loads: L2 stays warm because NO inv is ever
// issued. Barrier: per-block flag store (after __syncthreads vmcnt-drain) +
// all-blocks poll; workgroup fences for compiler ordering only.
//  part0 (blk 0..63):    layer0 step t      (t<=511)
//  part1 (blk 64..127):  xg1 for step t-1   (1<=t<=512)
//  part2 (blk 128..191): layer1 step t-2    (t>=2)

__global__ __launch_bounds__(256, 1) void gru_scan3_k(
    const u16* __restrict__ xg0,
    const u16* __restrict__ whh0, const u16* __restrict__ wih1,
    const u16* __restrict__ whh1,
    const float* __restrict__ bhh0, const float* __restrict__ bih1,
    const float* __restrict__ bhh1,
    const float* __restrict__ h0in,
    u16* __restrict__ h0b, u16* __restrict__ h1b,
    float* __restrict__ xg1, float* __restrict__ out,
    unsigned* __restrict__ flags) {
  const int blk = blockIdx.x;
  const int part = blk >> 6;
  const int sub = blk & 63;
  const int tid = threadIdx.x;
  const int w = tid >> 6, l = tid & 63;
  const int lrow = l & 15;
  const int kb = (l >> 4) * 8;

  const u16* Wsrc;
  int off0, off1, off2;
  if (part == 0) {
    Wsrc = whh0; off0 = sub * 16; off1 = HH + sub * 16; off2 = 2 * HH + sub * 16;
  } else if (part == 1) {
    Wsrc = wih1; off0 = sub * 48; off1 = sub * 48 + 16; off2 = sub * 48 + 32;
  } else {
    Wsrc = whh1; off0 = sub * 16; off1 = HH + sub * 16; off2 = 2 * HH + sub * 16;
  }

  // ---- W slice into registers (AGPR-able, static indexing only) ----
  short8 bw[3][32];
  {
    const u16* wp0 = Wsrc + (size_t)(off0 + lrow) * HH + kb;
    const u16* wp1 = Wsrc + (size_t)(off1 + lrow) * HH + kb;
    const u16* wp2 = Wsrc + (size_t)(off2 + lrow) * HH + kb;
#pragma unroll
    for (int ks = 0; ks < 32; ++ks) {
      bw[0][ks] = *(const short8*)(wp0 + ks * 32);
      bw[1][ks] = *(const short8*)(wp1 + ks * 32);
      bw[2][ks] = *(const short8*)(wp2 + ks * 32);
    }
  }

  const int j = sub * 16 + lrow;
  const int myrow0 = w * 16 + (l >> 4) * 4;  // rows myrow0..+3 for q=0..3

  float hreg[4] = {0.f, 0.f, 0.f, 0.f};
  float br = 0.f, bz = 0.f, bn_ = 0.f;
  float bv0 = 0.f, bv1 = 0.f, bv2 = 0.f;
  if (part == 0) {
    br = bhh0[j]; bz = bhh0[HH + j]; bn_ = bhh0[2 * HH + j];
#pragma unroll
    for (int q = 0; q < 4; ++q) hreg[q] = h0in[(myrow0 + q) * HH + j];
  } else if (part == 2) {
    br = bhh1[j]; bz = bhh1[HH + j]; bn_ = bhh1[2 * HH + j];
#pragma unroll
    for (int q = 0; q < 4; ++q) hreg[q] = h0in[BB * HH + (myrow0 + q) * HH + j];
  } else {
    bv0 = bih1[off0 + lrow]; bv1 = bih1[off1 + lrow]; bv2 = bih1[off2 + lrow];
  }

  const u16* Abase = (part == 2) ? h1b : h0b;
  const size_t arow = (size_t)(w * 16 + lrow) * HH + kb;

  for (int t = 0; t <= 513; ++t) {
    const int p0 = t & 1;
    const bool active = (part == 0) ? (t <= 511)
                      : (part == 1) ? (t >= 1 && t <= 512)
                                    : (t >= 2);
    if (active) {
      const u16* Ap = Abase + (size_t)p0 * (BB * HH) + arow;
      // prime 8-deep A ring (agent-scope: h state is cross-block data)
      short8 ar[8];
#pragma unroll
      for (int i = 0; i < 8; ++i) ar[i] = ld_s8_agent(Ap + i * 32);

      // prefetch x-gate slices early; consumed after the MFMA loop
      u16 xrv[4], xzv[4], xnv[4];
      if (part == 0) {
        const u16* xp = xg0 + (size_t)t * BB * G3;
#pragma unroll
        for (int q = 0; q < 4; ++q) {
          const u16* rp = xp + (size_t)(myrow0 + q) * G3;
          xrv[q] = rp[j]; xzv[q] = rp[HH + j]; xnv[q] = rp[2 * HH + j];
        }
      }
      float xg1v[3][4];
      if (part == 2) {
        const float* xp = xg1 + (size_t)p0 * (BB * G3);
#pragma unroll
        for (int q = 0; q < 4; ++q) {
          const float* rp = xp + (size_t)(myrow0 + q) * G3;
          xg1v[0][q] = __uint_as_float(ld_u32_agent((const unsigned*)(rp + j)));
          xg1v[1][q] = __uint_as_float(ld_u32_agent((const unsigned*)(rp + HH + j)));
          xg1v[2][q] = __uint_as_float(ld_u32_agent((const unsigned*)(rp + 2 * HH + j)));
        }
      }

      const f32x4 fzero = {0.f, 0.f, 0.f, 0.f};
      f32x4 acc0 = fzero, acc1 = fzero, acc2 = fzero;
#pragma unroll
      for (int ks = 0; ks < 32; ++ks) {
        short8 a = ar[ks & 7];
        if (ks < 24) ar[ks & 7] = ld_s8_agent(Ap + (ks + 8) * 32);
        acc0 = __builtin_amdgcn_mfma_f32_16x16x32_bf16(a, bw[0][ks], acc0, 0, 0, 0);
        acc1 = __builtin_amdgcn_mfma_f32_16x16x32_bf16(a, bw[1][ks], acc1, 0, 0, 0);
        acc2 = __builtin_amdgcn_mfma_f32_16x16x32_bf16(a, bw[2][ks], acc2, 0, 0, 0);
      }

      if (part == 1) {
        float* ox = xg1 + (size_t)(1 - p0) * (BB * G3);
        const int cc0 = off0 + lrow, cc1 = off1 + lrow, cc2 = off2 + lrow;
#pragma unroll
        for (int q = 0; q < 4; ++q) {
          int row = myrow0 + q;
          st_u32_agent((unsigned*)(ox + (size_t)row * G3 + cc0), __float_as_uint(acc0[q] + bv0));
          st_u32_agent((unsigned*)(ox + (size_t)row * G3 + cc1), __float_as_uint(acc1[q] + bv1));
          st_u32_agent((unsigned*)(ox + (size_t)row * G3 + cc2), __float_as_uint(acc2[q] + bv2));
        }
      } else {
        u16* hbn = ((part == 0) ? h0b : h1b) + (size_t)(1 - p0) * (BB * HH);
#pragma unroll
        for (int q = 0; q < 4; ++q) {
          float xr, xz, xn;
          if (part == 0) {
            xr = b2f(xrv[q]); xz = b2f(xzv[q]); xn = b2f(xnv[q]);
          } else {
            xr = xg1v[0][q]; xz = xg1v[1][q]; xn = xg1v[2][q];
          }
          float rr = acc0[q] + br + xr;
          float zz = acc1[q] + bz + xz;
          float nn = acc2[q] + bn_;
          float r = 1.f / (1.f + __expf(-rr));
          float z = 1.f / (1.f + __expf(-zz));
          float n = tanhf(xn + r * nn);
          float hv = (1.f - z) * n + z * hreg[q];
          hreg[q] = hv;
          // pack 2 cols (j even|odd) into u32 via lane-pair shfl, even lane stores
          int hb = (int)f2b(hv);
          int nb = __shfl_xor(hb, 1);
          if ((l & 1) == 0) {
            unsigned pk = (unsigned)(u16)hb | (((unsigned)(u16)nb) << 16);
            st_u32_agent((unsigned*)(hbn + (size_t)(myrow0 + q) * HH + j), pk);
          }
        }
      }
    }

    // ---- grid barrier: vmcnt-drained flag store + all-poll, no cache ops ----
    __syncthreads();  // all waves: compute+stores done (vmcnt 0 -> acks at LLC)
    if (tid == 0) {
      __builtin_amdgcn_fence(__ATOMIC_RELEASE, "workgroup");  // compiler order only
      st_u32_agent(&flags[blk], (unsigned)(t + 1));
    }
    const unsigned tgt = (unsigned)(t + 1);
    for (;;) {
      unsigned a0 = ld_u32_agent(&flags[l]);
      unsigned a1 = ld_u32_agent(&flags[l + 64]);
      unsigned a2 = ld_u32_agent(&flags[l + 128]);
      unsigned mn = a0 < a1 ? a0 : a1;
      mn = mn < a2 ? mn : a2;
      if (__all(mn >= tgt)) break;
      __builtin_amdgcn_s_sleep(1);
    }
    __builtin_amdgcn_fence(__ATOMIC_ACQUIRE, "workgroup");  // compiler order only
  }

  // ---- write h_n ----
  if (part == 0) {
#pragma unroll
    for (int q = 0; q < 4; ++q) out[(size_t)(myrow0 + q) * HH + j] = hreg[q];
  } else if (part == 2) {
#pragma unroll
    for (int q = 0; q < 4; ++q) out[BB * HH + (size_t)(myrow0 + q) * HH + j] = hreg[q];
  }
}

// ---------------- host ----------------

extern "C" void kernel_launch(void* const* d_in, const int* in_sizes, int n_in,
                              void* d_out, int out_size, void* d_ws, size_t ws_size,
                              hipStream_t stream) {
  const float* x   = (const float*)d_in[0];
  const float* h0  = (const float*)d_in[1];
  const float* wih = (const float*)d_in[2];
  const float* whh = (const float*)d_in[3];
  const float* bih = (const float*)d_in[4];
  const float* bhh = (const float*)d_in[5];
  float* out = (float*)d_out;

  char* ws = (char*)d_ws;
  size_t off = 0;
  auto alloc = [&](size_t bytes) -> void* {
    void* p = ws + off;
    off += (bytes + 255) & ~(size_t)255;
    return p;
  };
  u16* xbf   = (u16*)alloc((size_t)TT * BB * HH * 2);        // 64 MB
  u16* wihb  = (u16*)alloc((size_t)2 * G3 * HH * 2);         // 12.6 MB
  u16* whhb  = (u16*)alloc((size_t)2 * G3 * HH * 2);         // 12.6 MB
  u16* xg0   = (u16*)alloc((size_t)TT * BB * G3 * 2);        // 201 MB
  u16* h0b   = (u16*)alloc((size_t)2 * BB * HH * 2);
  u16* h1b   = (u16*)alloc((size_t)2 * BB * HH * 2);
  float* xg1 = (float*)alloc((size_t)2 * BB * G3 * 4);
  unsigned* flags = (unsigned*)alloc(NBLK * 4);

  hipMemsetAsync(flags, 0, NBLK * 4, stream);
  f32_to_bf16_k<<<2048, 256, 0, stream>>>(x, xbf, TT * BB * HH);
  f32_to_bf16_k<<<512, 256, 0, stream>>>(wih, wihb, 2 * G3 * HH);
  f32_to_bf16_k<<<512, 256, 0, stream>>>(whh, whhb, 2 * G3 * HH);
  init_h_k<<<256, 256, 0, stream>>>(h0, h0b, h1b);

  gemm_xg_k<<<6144, 256, 0, stream>>>(xbf, wihb, bih, xg0);

  gru_scan3_k<<<NBLK, 256, 0, stream>>>(xg0,
                                        whhb, wihb + (size_t)G3 * HH, whhb + (size_t)G3 * HH,
                                        bhh, bih + G3, bhh + G3, h0,
                                        h0b, h1b, xg1, out, flags);
}

// Round 6
// 7238.627 us; speedup vs baseline: 1.8022x; 1.0651x over previous
//
#include <hip/hip_runtime.h>

typedef unsigned short u16;
typedef unsigned long long u64;
typedef __attribute__((ext_vector_type(8))) short short8;
typedef __attribute__((ext_vector_type(4))) float f32x4;

#define HH 1024
#define BB 64
#define TT 512
#define G3 3072
#define NBLK 192

__device__ __forceinline__ u16 f2b(float f) {
  unsigned u = __float_as_uint(f);
  unsigned r = (u + 0x7fffu + ((u >> 16) & 1u)) >> 16;
  return (u16)r;
}
__device__ __forceinline__ float b2f(u16 h) {
  return __uint_as_float(((unsigned)h) << 16);
}

// agent-scope (LLC-coherent) accessors — per-access sc1, NO fences/wbl2/inv
__device__ __forceinline__ short8 ld_s8_agent(const u16* p) {
  union { short8 v; u64 d[2]; } s;
  s.d[0] = __hip_atomic_load((const u64*)p, __ATOMIC_RELAXED, __HIP_MEMORY_SCOPE_AGENT);
  s.d[1] = __hip_atomic_load((const u64*)(p + 4), __ATOMIC_RELAXED, __HIP_MEMORY_SCOPE_AGENT);
  return s.v;
}
__device__ __forceinline__ void st_u32_agent(unsigned* p, unsigned v) {
  __hip_atomic_store(p, v, __ATOMIC_RELAXED, __HIP_MEMORY_SCOPE_AGENT);
}
__device__ __forceinline__ unsigned ld_u32_agent(const unsigned* p) {
  return __hip_atomic_load(p, __ATOMIC_RELAXED, __HIP_MEMORY_SCOPE_AGENT);
}

// ---------------- elementwise converts / init ----------------

__global__ void f32_to_bf16_k(const float* __restrict__ s, u16* __restrict__ d, int n) {
  int stride = gridDim.x * blockDim.x * 4;
  for (int i = (blockIdx.x * blockDim.x + threadIdx.x) * 4; i < n; i += stride) {
    float4 v = *(const float4*)(s + i);
    uint2 p;
    p.x = (unsigned)f2b(v.x) | ((unsigned)f2b(v.y) << 16);
    p.y = (unsigned)f2b(v.z) | ((unsigned)f2b(v.w) << 16);
    *(uint2*)(d + i) = p;
  }
}

__global__ void init_h_k(const float* __restrict__ h0in, u16* __restrict__ h0b,
                         u16* __restrict__ h1b) {
  int i = blockIdx.x * blockDim.x + threadIdx.x;
  if (i < BB * HH) {
    h0b[i] = f2b(h0in[i]);
    h1b[i] = f2b(h0in[BB * HH + i]);
  }
}

// ---------------- phase A: xg0 = bf16(x @ W_ih0^T + b_ih0) ----------------

__global__ __launch_bounds__(256) void gemm_xg_k(
    const u16* __restrict__ A, const u16* __restrict__ Wt,
    const float* __restrict__ bias, u16* __restrict__ C) {
  const int bm = blockIdx.x / 24;
  const int bn = blockIdx.x % 24;
  const int m0 = bm * 128, n0 = bn * 128;
  __shared__ __align__(16) u16 al[128 * 40];
  __shared__ __align__(16) u16 bl[128 * 40];
  const int tid = threadIdx.x;
  const int w = tid >> 6, l = tid & 63;
  const int wr = w >> 1, wc = w & 1;
  const int c0 = tid, c1 = tid + 256;
  const int r0 = c0 >> 2, s0 = c0 & 3, r1 = c1 >> 2, s1 = c1 & 3;

  const f32x4 fzero = {0.f, 0.f, 0.f, 0.f};
  f32x4 acc[4][4];
#pragma unroll
  for (int i = 0; i < 4; ++i)
#pragma unroll
    for (int j = 0; j < 4; ++j) acc[i][j] = fzero;

  const u16* a0p = A + (size_t)(m0 + r0) * 1024 + s0 * 8;
  const u16* a1p = A + (size_t)(m0 + r1) * 1024 + s1 * 8;
  const u16* b0p = Wt + (size_t)(n0 + r0) * 1024 + s0 * 8;
  const u16* b1p = Wt + (size_t)(n0 + r1) * 1024 + s1 * 8;

  int4 va0 = *(const int4*)(a0p);
  int4 va1 = *(const int4*)(a1p);
  int4 vb0 = *(const int4*)(b0p);
  int4 vb1 = *(const int4*)(b1p);

  for (int kt = 0; kt < 32; ++kt) {
    __syncthreads();
    *(int4*)&al[r0 * 40 + s0 * 8] = va0;
    *(int4*)&al[r1 * 40 + s1 * 8] = va1;
    *(int4*)&bl[r0 * 40 + s0 * 8] = vb0;
    *(int4*)&bl[r1 * 40 + s1 * 8] = vb1;
    __syncthreads();
    if (kt < 31) {
      va0 = *(const int4*)(a0p + (kt + 1) * 32);
      va1 = *(const int4*)(a1p + (kt + 1) * 32);
      vb0 = *(const int4*)(b0p + (kt + 1) * 32);
      vb1 = *(const int4*)(b1p + (kt + 1) * 32);
    }
    short8 af[4], bf[4];
#pragma unroll
    for (int i = 0; i < 4; ++i)
      af[i] = *(const short8*)&al[(wr * 64 + i * 16 + (l & 15)) * 40 + (l >> 4) * 8];
#pragma unroll
    for (int j = 0; j < 4; ++j)
      bf[j] = *(const short8*)&bl[(wc * 64 + j * 16 + (l & 15)) * 40 + (l >> 4) * 8];
#pragma unroll
    for (int i = 0; i < 4; ++i)
#pragma unroll
      for (int j = 0; j < 4; ++j)
        acc[i][j] = __builtin_amdgcn_mfma_f32_16x16x32_bf16(af[i], bf[j], acc[i][j], 0, 0, 0);
  }

#pragma unroll
  for (int i = 0; i < 4; ++i) {
#pragma unroll
    for (int j = 0; j < 4; ++j) {
      int col = n0 + wc * 64 + j * 16 + (l & 15);
      float bv = bias[col];
#pragma unroll
      for (int q = 0; q < 4; ++q) {
        int row = m0 + wr * 64 + i * 16 + (l >> 4) * 4 + q;
        C[(size_t)row * G3 + col] = f2b(acc[i][j][q] + bv);
      }
    }
  }
}

// ---------------- persistent fused scan, v5 ----------------
// Back to the R4-proven coherence scheme (relaxed agent atomics, flag-store
// barrier, no fences-with-cache-ops, no inline asm). Changes vs R4:
//  * W slice lives in LDS (96 KB, XOR-swizzled) -> deterministic residency,
//    zero spill/remat risk, trivial VGPR pressure.
//  * A (h state) loaded as a flat 32-wide batch of agent-scope atomic pairs
//    -> all 64 dwordx2 loads in flight at once, ~1 LLC latency total.
//  part0 (blk 0..63):    layer0 step t      (t<=511)
//  part1 (blk 64..127):  xg1 for step t-1   (1<=t<=512)
//  part2 (blk 128..191): layer1 step t-2    (t>=2)

__global__ __launch_bounds__(256, 1) void gru_scan5_k(
    const u16* __restrict__ xg0,
    const u16* __restrict__ whh0, const u16* __restrict__ wih1,
    const u16* __restrict__ whh1,
    const float* __restrict__ bhh0, const float* __restrict__ bih1,
    const float* __restrict__ bhh1,
    const float* __restrict__ h0in,
    u16* __restrict__ h0b, u16* __restrict__ h1b,
    float* __restrict__ xg1, float* __restrict__ out,
    unsigned* __restrict__ flags) {
  const int blk = blockIdx.x;
  const int part = blk >> 6;
  const int sub = blk & 63;
  const int tid = threadIdx.x;
  const int w = tid >> 6, l = tid & 63;
  const int lrow = l & 15;
  const int kb = (l >> 4) * 8;

  const u16* Wsrc;
  int off0, off1, off2;
  if (part == 0) {
    Wsrc = whh0; off0 = sub * 16; off1 = HH + sub * 16; off2 = 2 * HH + sub * 16;
  } else if (part == 1) {
    Wsrc = wih1; off0 = sub * 48; off1 = sub * 48 + 16; off2 = sub * 48 + 32;
  } else {
    Wsrc = whh1; off0 = sub * 16; off1 = HH + sub * 16; off2 = 2 * HH + sub * 16;
  }

  // ---- W slice into LDS: 48 rows x 1024, elem idx ^= (row&7)<<3 ----
  __shared__ __align__(16) u16 wlds[48 * 1024];
  for (int i = tid; i < 6144; i += 256) {
    int r = i >> 7;
    int c = i & 127;
    int g = r >> 4;
    int wrow = (g == 0 ? off0 : (g == 1 ? off1 : off2)) + (r & 15);
    int4 v = *(const int4*)(Wsrc + (size_t)wrow * 1024 + c * 8);
    int idx = r * 1024 + ((c * 8) ^ ((r & 7) << 3));
    *(int4*)&wlds[idx] = v;
  }
  __syncthreads();

  const int j = sub * 16 + lrow;
  const int myrow0 = w * 16 + (l >> 4) * 4;  // rows myrow0..+3 for q=0..3
  const int rr0 = lrow, rr1 = 16 + lrow, rr2 = 32 + lrow;
  const int sx = (lrow & 7) << 3;  // (rr&7) identical for all three gates

  float hreg[4] = {0.f, 0.f, 0.f, 0.f};
  float br = 0.f, bz = 0.f, bn_ = 0.f;
  float bv0 = 0.f, bv1 = 0.f, bv2 = 0.f;
  if (part == 0) {
    br = bhh0[j]; bz = bhh0[HH + j]; bn_ = bhh0[2 * HH + j];
#pragma unroll
    for (int q = 0; q < 4; ++q) hreg[q] = h0in[(myrow0 + q) * HH + j];
  } else if (part == 2) {
    br = bhh1[j]; bz = bhh1[HH + j]; bn_ = bhh1[2 * HH + j];
#pragma unroll
    for (int q = 0; q < 4; ++q) hreg[q] = h0in[BB * HH + (myrow0 + q) * HH + j];
  } else {
    bv0 = bih1[off0 + lrow]; bv1 = bih1[off1 + lrow]; bv2 = bih1[off2 + lrow];
  }

  const u16* Abase = (part == 2) ? h1b : h0b;
  const size_t arow = (size_t)(w * 16 + lrow) * HH + kb;

  for (int t = 0; t <= 513; ++t) {
    const int p0 = t & 1;
    const bool active = (part == 0) ? (t <= 511)
                      : (part == 1) ? (t >= 1 && t <= 512)
                                    : (t >= 2);
    if (active) {
      const u16* Ap = Abase + (size_t)p0 * (BB * HH) + arow;

      // ---- flat 32-wide A batch: 64 independent dwordx2 sc1 loads ----
      short8 ar[32];
#pragma unroll
      for (int ks = 0; ks < 32; ++ks) ar[ks] = ld_s8_agent(Ap + ks * 32);

      // ---- overlap: x-gate loads ----
      u16 xrv[4], xzv[4], xnv[4];
      if (part == 0) {
        const u16* xp = xg0 + (size_t)t * BB * G3;
#pragma unroll
        for (int q = 0; q < 4; ++q) {
          const u16* rp = xp + (size_t)(myrow0 + q) * G3;
          xrv[q] = rp[j]; xzv[q] = rp[HH + j]; xnv[q] = rp[2 * HH + j];
        }
      }
      float xg1v[3][4];
      if (part == 2) {
        const float* xp = xg1 + (size_t)p0 * (BB * G3);
#pragma unroll
        for (int q = 0; q < 4; ++q) {
          const float* rp = xp + (size_t)(myrow0 + q) * G3;
          xg1v[0][q] = __uint_as_float(ld_u32_agent((const unsigned*)(rp + j)));
          xg1v[1][q] = __uint_as_float(ld_u32_agent((const unsigned*)(rp + HH + j)));
          xg1v[2][q] = __uint_as_float(ld_u32_agent((const unsigned*)(rp + 2 * HH + j)));
        }
      }

      const f32x4 fzero = {0.f, 0.f, 0.f, 0.f};
      f32x4 acc0 = fzero, acc1 = fzero, acc2 = fzero;
#pragma unroll
      for (int ks = 0; ks < 32; ++ks) {
        int ke = kb + ks * 32;
        short8 b0 = *(const short8*)&wlds[rr0 * 1024 + (ke ^ sx)];
        short8 b1 = *(const short8*)&wlds[rr1 * 1024 + (ke ^ sx)];
        short8 b2 = *(const short8*)&wlds[rr2 * 1024 + (ke ^ sx)];
        acc0 = __builtin_amdgcn_mfma_f32_16x16x32_bf16(ar[ks], b0, acc0, 0, 0, 0);
        acc1 = __builtin_amdgcn_mfma_f32_16x16x32_bf16(ar[ks], b1, acc1, 0, 0, 0);
        acc2 = __builtin_amdgcn_mfma_f32_16x16x32_bf16(ar[ks], b2, acc2, 0, 0, 0);
      }

      if (part == 1) {
        float* ox = xg1 + (size_t)(1 - p0) * (BB * G3);
        const int cc0 = off0 + lrow, cc1 = off1 + lrow, cc2 = off2 + lrow;
#pragma unroll
        for (int q = 0; q < 4; ++q) {
          int row = myrow0 + q;
          st_u32_agent((unsigned*)(ox + (size_t)row * G3 + cc0), __float_as_uint(acc0[q] + bv0));
          st_u32_agent((unsigned*)(ox + (size_t)row * G3 + cc1), __float_as_uint(acc1[q] + bv1));
          st_u32_agent((unsigned*)(ox + (size_t)row * G3 + cc2), __float_as_uint(acc2[q] + bv2));
        }
      } else {
        u16* hbn = ((part == 0) ? h0b : h1b) + (size_t)(1 - p0) * (BB * HH);
#pragma unroll
        for (int q = 0; q < 4; ++q) {
          float xr, xz, xn;
          if (part == 0) {
            xr = b2f(xrv[q]); xz = b2f(xzv[q]); xn = b2f(xnv[q]);
          } else {
            xr = xg1v[0][q]; xz = xg1v[1][q]; xn = xg1v[2][q];
          }
          float rr = acc0[q] + br + xr;
          float zz = acc1[q] + bz + xz;
          float nn = acc2[q] + bn_;
          float r = 1.f / (1.f + __expf(-rr));
          float z = 1.f / (1.f + __expf(-zz));
          float n = tanhf(xn + r * nn);
          float hv = (1.f - z) * n + z * hreg[q];
          hreg[q] = hv;
          // pack 2 cols (j even|odd) into u32 via lane-pair shfl, even lane stores
          int hb = (int)f2b(hv);
          int nb = __shfl_xor(hb, 1);
          if ((l & 1) == 0) {
            unsigned pk = (unsigned)(u16)hb | (((unsigned)(u16)nb) << 16);
            st_u32_agent((unsigned*)(hbn + (size_t)(myrow0 + q) * HH + j), pk);
          }
        }
      }
    }

    // ---- grid barrier: vmcnt-drained flag store + all-poll, no cache ops ----
    __syncthreads();  // all waves: compute+stores done (vmcnt 0 -> acks at LLC)
    if (tid == 0) {
      __builtin_amdgcn_fence(__ATOMIC_RELEASE, "workgroup");  // compiler order only
      st_u32_agent(&flags[blk], (unsigned)(t + 1));
    }
    const unsigned tgt = (unsigned)(t + 1);
    for (;;) {
      unsigned a0 = ld_u32_agent(&flags[l]);
      unsigned a1 = ld_u32_agent(&flags[l + 64]);
      unsigned a2 = ld_u32_agent(&flags[l + 128]);
      unsigned mn = a0 < a1 ? a0 : a1;
      mn = mn < a2 ? mn : a2;
      if (__all(mn >= tgt)) break;
      __builtin_amdgcn_s_sleep(1);
    }
    __builtin_amdgcn_fence(__ATOMIC_ACQUIRE, "workgroup");  // compiler order only
  }

  // ---- write h_n ----
  if (part == 0) {
#pragma unroll
    for (int q = 0; q < 4; ++q) out[(size_t)(myrow0 + q) * HH + j] = hreg[q];
  } else if (part == 2) {
#pragma unroll
    for (int q = 0; q < 4; ++q) out[BB * HH + (size_t)(myrow0 + q) * HH + j] = hreg[q];
  }
}

// ---------------- host ----------------

extern "C" void kernel_launch(void* const* d_in, const int* in_sizes, int n_in,
                              void* d_out, int out_size, void* d_ws, size_t ws_size,
                              hipStream_t stream) {
  const float* x   = (const float*)d_in[0];
  const float* h0  = (const float*)d_in[1];
  const float* wih = (const float*)d_in[2];
  const float* whh = (const float*)d_in[3];
  const float* bih = (const float*)d_in[4];
  const float* bhh = (const float*)d_in[5];
  float* out = (float*)d_out;

  char* ws = (char*)d_ws;
  size_t off = 0;
  auto alloc = [&](size_t bytes) -> void* {
    void* p = ws + off;
    off += (bytes + 255) & ~(size_t)255;
    return p;
  };
  u16* xbf   = (u16*)alloc((size_t)TT * BB * HH * 2);        // 64 MB
  u16* wihb  = (u16*)alloc((size_t)2 * G3 * HH * 2);         // 12.6 MB
  u16* whhb  = (u16*)alloc((size_t)2 * G3 * HH * 2);         // 12.6 MB
  u16* xg0   = (u16*)alloc((size_t)TT * BB * G3 * 2);        // 201 MB
  u16* h0b   = (u16*)alloc((size_t)2 * BB * HH * 2);
  u16* h1b   = (u16*)alloc((size_t)2 * BB * HH * 2);
  float* xg1 = (float*)alloc((size_t)2 * BB * G3 * 4);
  unsigned* flags = (unsigned*)alloc(NBLK * 4);

  hipMemsetAsync(flags, 0, NBLK * 4, stream);
  f32_to_bf16_k<<<2048, 256, 0, stream>>>(x, xbf, TT * BB * HH);
  f32_to_bf16_k<<<512, 256, 0, stream>>>(wih, wihb, 2 * G3 * HH);
  f32_to_bf16_k<<<512, 256, 0, stream>>>(whh, whhb, 2 * G3 * HH);
  init_h_k<<<256, 256, 0, stream>>>(h0, h0b, h1b);

  gemm_xg_k<<<6144, 256, 0, stream>>>(xbf, wihb, bih, xg0);

  gru_scan5_k<<<NBLK, 256, 0, stream>>>(xg0,
                                        whhb, wihb + (size_t)G3 * HH, whhb + (size_t)G3 * HH,
                                        bhh, bih + G3, bhh + G3, h0,
                                        h0b, h1b, xg1, out, flags);
}